// Round 2
// baseline (632.914 us; speedup 1.0000x reference)
//
#include <hip/hip_runtime.h>
#include <hip/hip_bf16.h>

// Problem constants (from reference setup_inputs)
#define BB 2
#define NH 4
#define NN 2304
#define DIM 64
#define DH 8
#define HID 32
#define KN 314   // neighbors per point

// Workspace layout (floats):
#define QKV_OFF 0
#define QKV_SZ  (BB*NN*96)            // 442368
#define A_OFF   (QKV_OFF + QKV_SZ)    // 442368
#define A_SZ    (BB*NH*NN*HID)        // 589824
#define BK_OFF  (A_OFF + A_SZ)        // 1032192
#define BK_SZ   (BB*NH*NN*HID)
#define V_OFF   (BK_OFF + BK_SZ)      // 1622016
#define V_SZ    (BB*NH*NN*DH)         // 147456
#define DEN_OFF (V_OFF + V_SZ)        // 1769472
#define DEN_SZ  (BB*NH*KN*DH)         // 20096
#define AGG_OFF (DEN_OFF + DEN_SZ)    // 1789568
#define AGG_SZ  (BB*NH*NN*DH)         // 147456
// total = 1937024 floats = 7.75 MB

// ---------------- K1: qkv = x @ w_qkv  (f32) ----------------
__global__ void qkv_kernel(const float* __restrict__ x, const float* __restrict__ w_qkv, float* ws){
    int t = blockIdx.x*256 + threadIdx.x;
    if (t >= BB*NN*96) return;
    int c = t % 96;
    int p = (t / 96) % NN;
    int b = t / (96*NN);
    const float* xr = x + (b*NN + p)*DIM;
    float acc = 0.f;
    #pragma unroll 8
    for (int dd=0; dd<DIM; dd++)
        acc = fmaf(xr[dd], w_qkv[dd*96 + c], acc);
    ws[QKV_OFF + (b*NN + p)*96 + c] = acc;
}

// ---------------- K2: A = w1.q + b1 ; Bk = w1.k ; V copy ----------------
__global__ void ab_kernel(const float* __restrict__ w1, const float* __restrict__ b1, float* ws){
    int t = blockIdx.x*256 + threadIdx.x;
    if (t >= BB*NH*NN*HID) return;
    int e  = t % HID;
    int p  = (t / HID) % NN;
    int hh = (t / (HID*NN)) % NH;
    int b  = t / (HID*NN*NH);
    const float* qkv = ws + QKV_OFF + (b*NN + p)*96;
    const float* w1r = w1 + (hh*HID + e)*DH;
    float sa = b1[hh*HID + e];
    float sb = 0.f;
    #pragma unroll
    for (int d=0; d<DH; d++){
        float wv = w1r[d];
        sa = fmaf(wv, qkv[hh*DH + d],      sa);  // q part
        sb = fmaf(wv, qkv[32 + hh*DH + d], sb);  // k part
    }
    int base = ((b*NH + hh)*NN + p);
    ws[A_OFF  + base*HID + e] = sa;
    ws[BK_OFF + base*HID + e] = sb;
    if (e < DH)
        ws[V_OFF + base*DH + e] = qkv[64 + hh*DH + e];  // v copy
}

// ---------------- K3: pass 1 — den[b,h,j,d] = sum_i exp(sim) ----------------
// grid: (320, NH, BB); blockIdx.x = sg*8 + ic ; block = 256 (4 waves)
// lane = g*8 + d : group g owns slot j = sg*8+g, lane owns one d.
__global__ __launch_bounds__(256) void pass1_kernel(const int* __restrict__ idx,
                                                    const float* __restrict__ w2,
                                                    const float* __restrict__ b2, float* ws){
    int sgic = blockIdx.x, hh = blockIdx.y, b = blockIdx.z;
    int sg = sgic >> 3, ic = sgic & 7;
    int w = threadIdx.x >> 6, lane = threadIdx.x & 63;
    int g = lane >> 3, dd = lane & 7;
    int j = sg*8 + g;
    bool jv = (j < KN);
    int jj = jv ? j : 0;

    float w2r[HID];
    const float* w2p = w2 + (hh*DH + dd)*HID;
    #pragma unroll
    for (int e=0; e<HID; e++) w2r[e] = w2p[e];
    float b2v = b2[hh*DH + dd];

    const float* Abuf = ws + A_OFF  + (size_t)(b*NH + hh)*NN*HID;
    const float* Bbuf = ws + BK_OFF + (size_t)(b*NH + hh)*NN*HID;

    float den_acc = 0.f;
    int i0 = ic*288 + w*72;
    for (int ii=0; ii<72; ii++){
        int i = i0 + ii;
        int p = idx[i*KN + jj];
        float Ar[HID], Br[HID];
        const float4* ap = (const float4*)(Abuf + (size_t)i*HID);
        const float4* bp = (const float4*)(Bbuf + (size_t)p*HID);
        #pragma unroll
        for (int e4=0; e4<8; e4++){
            float4 av = ap[e4]; float4 bv = bp[e4];
            Ar[4*e4+0]=av.x; Ar[4*e4+1]=av.y; Ar[4*e4+2]=av.z; Ar[4*e4+3]=av.w;
            Br[4*e4+0]=bv.x; Br[4*e4+1]=bv.y; Br[4*e4+2]=bv.z; Br[4*e4+3]=bv.w;
        }
        float sim = b2v;
        #pragma unroll
        for (int e=0; e<HID; e++)
            sim = fmaf(w2r[e], fmaxf(Ar[e]-Br[e], 0.f), sim);
        if (jv) den_acc += __expf(sim);
    }

    __shared__ float red[256];
    red[threadIdx.x] = den_acc;
    __syncthreads();
    if (w == 0 && jv){
        float s = red[lane] + red[lane+64] + red[lane+128] + red[lane+192];
        atomicAdd(ws + DEN_OFF + ((size_t)(b*NH + hh)*KN + j)*DH + dd, s);
    }
}

// ---------------- K3.5: invert den in place ----------------
__global__ void invden_kernel(float* ws){
    int t = blockIdx.x*256 + threadIdx.x;
    if (t < DEN_SZ){
        float* d = ws + DEN_OFF;
        d[t] = 1.0f / d[t];
    }
}

// ---------------- K4: pass 2 — agg[b,h,i,d] = sum_j exp(sim)*invden*v ----------------
// grid: (72, NH, BB); block = 256 (4 waves), each wave does 8 i's.
__global__ __launch_bounds__(256) void pass2_kernel(const int* __restrict__ idx,
                                                    const float* __restrict__ w2,
                                                    const float* __restrict__ b2, float* ws){
    int ic = blockIdx.x, hh = blockIdx.y, b = blockIdx.z;
    int w = threadIdx.x >> 6, lane = threadIdx.x & 63;
    int g = lane >> 3, dd = lane & 7;

    float w2r[HID];
    const float* w2p = w2 + (hh*DH + dd)*HID;
    #pragma unroll
    for (int e=0; e<HID; e++) w2r[e] = w2p[e];
    float b2v = b2[hh*DH + dd];

    const float* Abuf  = ws + A_OFF  + (size_t)(b*NH + hh)*NN*HID;
    const float* Bbuf  = ws + BK_OFF + (size_t)(b*NH + hh)*NN*HID;
    const float* Vbuf  = ws + V_OFF  + (size_t)(b*NH + hh)*NN*DH;
    const float* invd  = ws + DEN_OFF + (size_t)(b*NH + hh)*KN*DH;
    float*       agg   = ws + AGG_OFF + (size_t)(b*NH + hh)*NN*DH;

    int i0 = ic*32 + w*8;
    for (int ii=0; ii<8; ii++){
        int i = i0 + ii;
        float Ar[HID];
        const float4* ap = (const float4*)(Abuf + (size_t)i*HID);
        #pragma unroll
        for (int e4=0; e4<8; e4++){
            float4 av = ap[e4];
            Ar[4*e4+0]=av.x; Ar[4*e4+1]=av.y; Ar[4*e4+2]=av.z; Ar[4*e4+3]=av.w;
        }
        float acc = 0.f;
        for (int sg=0; sg<40; sg++){
            int j = sg*8 + g;
            bool jv = (j < KN);
            int p = idx[i*KN + (jv ? j : 0)];
            float Br[HID];
            const float4* bp = (const float4*)(Bbuf + (size_t)p*HID);
            #pragma unroll
            for (int e4=0; e4<8; e4++){
                float4 bv = bp[e4];
                Br[4*e4+0]=bv.x; Br[4*e4+1]=bv.y; Br[4*e4+2]=bv.z; Br[4*e4+3]=bv.w;
            }
            float sim = b2v;
            #pragma unroll
            for (int e=0; e<HID; e++)
                sim = fmaf(w2r[e], fmaxf(Ar[e]-Br[e], 0.f), sim);
            if (jv){
                float attn = __expf(sim) * invd[j*DH + dd];
                acc = fmaf(attn, Vbuf[(size_t)p*DH + dd], acc);
            }
        }
        // reduce over the 8 slot-groups (lanes stride 8, same d)
        acc += __shfl_xor(acc, 8, 64);
        acc += __shfl_xor(acc, 16, 64);
        acc += __shfl_xor(acc, 32, 64);
        if (g == 0) agg[(size_t)i*DH + dd] = acc;
    }
}

// ---------------- K5: out = agg @ w_out + b_out ----------------
__global__ void out_kernel(const float* __restrict__ w_out, const float* __restrict__ b_out,
                           const float* __restrict__ ws, float* __restrict__ out){
    int t = blockIdx.x*256 + threadIdx.x;
    if (t >= BB*NN*DIM) return;
    int c = t % DIM;
    int p = (t / DIM) % NN;
    int b = t / (DIM*NN);
    const float* agg = ws + AGG_OFF;
    float s = b_out[c];
    #pragma unroll
    for (int f=0; f<32; f++){
        int hh = f >> 3, d = f & 7;
        s = fmaf(agg[(((size_t)(b*NH + hh)*NN) + p)*DH + d], w_out[f*DIM + c], s);
    }
    out[t] = s;
}

extern "C" void kernel_launch(void* const* d_in, const int* in_sizes, int n_in,
                              void* d_out, int out_size, void* d_ws, size_t ws_size,
                              hipStream_t stream){
    const float* x     = (const float*)d_in[0];
    const int*   idx   = (const int*)d_in[1];
    const float* w_qkv = (const float*)d_in[2];
    const float* w1    = (const float*)d_in[3];
    const float* b1    = (const float*)d_in[4];
    const float* w2    = (const float*)d_in[5];
    const float* b2    = (const float*)d_in[6];
    const float* w_out = (const float*)d_in[7];
    const float* b_out = (const float*)d_in[8];
    float* ws  = (float*)d_ws;
    float* out = (float*)d_out;

    // zero the softmax denominators (ws is poisoned, not re-zeroed between replays)
    hipMemsetAsync(ws + DEN_OFF, 0, DEN_SZ*sizeof(float), stream);

    qkv_kernel  <<<(BB*NN*96 + 255)/256, 256, 0, stream>>>(x, w_qkv, ws);
    ab_kernel   <<<(BB*NH*NN*HID + 255)/256, 256, 0, stream>>>(w1, b1, ws);
    pass1_kernel<<<dim3(320, NH, BB), 256, 0, stream>>>(idx, w2, b2, ws);
    invden_kernel<<<(DEN_SZ + 255)/256, 256, 0, stream>>>(ws);
    pass2_kernel<<<dim3(72, NH, BB), 256, 0, stream>>>(idx, w2, b2, ws);
    out_kernel  <<<(BB*NN*DIM + 255)/256, 256, 0, stream>>>(w_out, b_out, ws, out);
}

// Round 3
// 494.372 us; speedup vs baseline: 1.2802x; 1.2802x over previous
//
#include <hip/hip_runtime.h>
#include <hip/hip_bf16.h>

// Problem constants (from reference setup_inputs)
#define BB 2
#define NH 4
#define NN 2304
#define DIM 64
#define DH 8
#define HID 32
#define KN 314   // neighbors per point

// Workspace layout (floats):
#define QKV_OFF 0
#define QKV_SZ  (BB*NN*96)            // 442368
#define A_OFF   (QKV_OFF + QKV_SZ)    // 442368
#define A_SZ    (BB*NH*NN*HID)        // 589824
#define BK_OFF  (A_OFF + A_SZ)        // 1032192
#define BK_SZ   (BB*NH*NN*HID)
#define V_OFF   (BK_OFF + BK_SZ)      // 1622016
#define V_SZ    (BB*NH*NN*DH)         // 147456
#define DEN_OFF (V_OFF + V_SZ)        // 1769472
#define DEN_SZ  (BB*NH*KN*DH)         // 20096
#define AGG_OFF (DEN_OFF + DEN_SZ)    // 1789568
#define AGG_SZ  (BB*NH*NN*DH)         // 147456

// ---------------- K1: qkv = x @ w_qkv  (f32) ----------------
__global__ void qkv_kernel(const float* __restrict__ x, const float* __restrict__ w_qkv, float* ws){
    int t = blockIdx.x*256 + threadIdx.x;
    if (t >= BB*NN*96) return;
    int c = t % 96;
    int p = (t / 96) % NN;
    int b = t / (96*NN);
    const float* xr = x + (b*NN + p)*DIM;
    float acc = 0.f;
    #pragma unroll 8
    for (int dd=0; dd<DIM; dd++)
        acc = fmaf(xr[dd], w_qkv[dd*96 + c], acc);
    ws[QKV_OFF + (b*NN + p)*96 + c] = acc;
}

// ---------------- K2: A = w1.q + b1 ; Bk = w1.k ; V copy ----------------
__global__ void ab_kernel(const float* __restrict__ w1, const float* __restrict__ b1, float* ws){
    int t = blockIdx.x*256 + threadIdx.x;
    if (t >= BB*NH*NN*HID) return;
    int e  = t % HID;
    int p  = (t / HID) % NN;
    int hh = (t / (HID*NN)) % NH;
    int b  = t / (HID*NN*NH);
    const float* qkv = ws + QKV_OFF + (b*NN + p)*96;
    const float* w1r = w1 + (hh*HID + e)*DH;
    float sa = b1[hh*HID + e];
    float sb = 0.f;
    #pragma unroll
    for (int d=0; d<DH; d++){
        float wv = w1r[d];
        sa = fmaf(wv, qkv[hh*DH + d],      sa);  // q part
        sb = fmaf(wv, qkv[32 + hh*DH + d], sb);  // k part
    }
    int base = ((b*NH + hh)*NN + p);
    ws[A_OFF  + base*HID + e] = sa;
    ws[BK_OFF + base*HID + e] = sb;
    if (e < DH)
        ws[V_OFF + base*DH + e] = qkv[64 + hh*DH + e];  // v copy
}

// Per-lane w2 slice in bit-reversed d order so the split-butterfly lands d=dd on lane dd.
// w2s[m][t] = w2[hh, bitrev3(m), 4*dd + t]
__device__ __forceinline__ void load_w2s(const float* __restrict__ w2, int hh, int dd, float w2s[8][4]){
    #pragma unroll
    for (int m=0; m<8; m++){
        int d = ((m&1)<<2) | (m&2) | ((m>>2)&1);   // bitrev3(m)
        const float* wp = w2 + (hh*DH + d)*HID + 4*dd;
        w2s[m][0]=wp[0]; w2s[m][1]=wp[1]; w2s[m][2]=wp[2]; w2s[m][3]=wp[3];
    }
}

// partials pr[8] (bit-rev d order) -> full sim for d=dd on lane dd (within 8-lane group)
__device__ __forceinline__ float butterfly8(float pr[8], int dd){
    int b0 = dd&1, b1 = (dd>>1)&1, b2b = (dd>>2)&1;
    float q[4];
    #pragma unroll
    for (int t=0; t<4; t++){
        float send = pr[4*(1-b0)+t];
        float recv = __shfl_xor(send, 1, 64);
        q[t] = pr[4*b0+t] + recv;
    }
    float r[2];
    #pragma unroll
    for (int t=0; t<2; t++){
        float send = q[2*(1-b1)+t];
        float recv = __shfl_xor(send, 2, 64);
        r[t] = q[2*b1+t] + recv;
    }
    float send = r[1-b2b];
    float recv = __shfl_xor(send, 4, 64);
    return r[b2b] + recv;
}

// ---------------- K3: pass 1 — den[b,h,j,d] = sum_i exp(sim) ----------------
// grid: (320, NH, BB); blockIdx.x = sg*8 + ic ; block = 256 (4 waves)
// lane = g*8 + dd : group g owns slot j = sg*8+g; lane owns e-slice [4dd,4dd+4).
__global__ __launch_bounds__(256) void pass1_kernel(const int* __restrict__ idx,
                                                    const float* __restrict__ w2,
                                                    const float* __restrict__ b2, float* ws){
    int sgic = blockIdx.x, hh = blockIdx.y, b = blockIdx.z;
    int sg = sgic >> 3, ic = sgic & 7;
    int w = threadIdx.x >> 6, lane = threadIdx.x & 63;
    int g = lane >> 3, dd = lane & 7;
    int j = sg*8 + g;
    bool jv = (j < KN);
    int jj = jv ? j : (KN-1);

    float w2s[8][4];
    load_w2s(w2, hh, dd, w2s);
    float b2v = b2[hh*DH + dd];

    const float* Abuf = ws + A_OFF  + (size_t)(b*NH + hh)*NN*HID;
    const float* Bbuf = ws + BK_OFF + (size_t)(b*NH + hh)*NN*HID;

    float den_acc = 0.f;
    int i0 = ic*288 + w*72;
    for (int ii=0; ii<72; ii++){
        int i = i0 + ii;
        int p = idx[i*KN + jj];
        float4 av = *(const float4*)(Abuf + (size_t)i*HID + 4*dd);
        float4 bv = *(const float4*)(Bbuf + (size_t)p*HID + 4*dd);
        float r0 = fmaxf(av.x-bv.x, 0.f), r1 = fmaxf(av.y-bv.y, 0.f);
        float r2 = fmaxf(av.z-bv.z, 0.f), r3 = fmaxf(av.w-bv.w, 0.f);
        float pr[8];
        #pragma unroll
        for (int m=0; m<8; m++)
            pr[m] = fmaf(w2s[m][0],r0, fmaf(w2s[m][1],r1, fmaf(w2s[m][2],r2, w2s[m][3]*r3)));
        float sim = butterfly8(pr, dd) + b2v;
        den_acc += __expf(sim);
    }
    if (!jv) den_acc = 0.f;

    __shared__ float red[256];
    red[threadIdx.x] = den_acc;
    __syncthreads();
    if (w == 0 && jv){
        float s = red[lane] + red[lane+64] + red[lane+128] + red[lane+192];
        atomicAdd(ws + DEN_OFF + ((size_t)(b*NH + hh)*KN + j)*DH + dd, s);
    }
}

// ---------------- K3.5: invert den in place ----------------
__global__ void invden_kernel(float* ws){
    int t = blockIdx.x*256 + threadIdx.x;
    if (t < DEN_SZ){
        float* d = ws + DEN_OFF;
        d[t] = 1.0f / d[t];
    }
}

// ---------------- K4: pass 2 — agg[b,h,i,d] = sum_j exp(sim)*invden*v ----------------
// grid: (288, NH, BB); block = 256 (4 waves); each wave does 2 i's.
// lane = g*8 + dd : group g owns j = sg*8+g; lane owns e-slice [4dd,4dd+4).
__global__ __launch_bounds__(256) void pass2_kernel(const int* __restrict__ idx,
                                                    const float* __restrict__ w2,
                                                    const float* __restrict__ b2, float* ws){
    int ic = blockIdx.x, hh = blockIdx.y, b = blockIdx.z;
    int w = threadIdx.x >> 6, lane = threadIdx.x & 63;
    int g = lane >> 3, dd = lane & 7;

    float w2s[8][4];
    load_w2s(w2, hh, dd, w2s);
    float b2v = b2[hh*DH + dd];

    const float* Abuf = ws + A_OFF  + (size_t)(b*NH + hh)*NN*HID;
    const float* Bbuf = ws + BK_OFF + (size_t)(b*NH + hh)*NN*HID;
    const float* Vbuf = ws + V_OFF  + (size_t)(b*NH + hh)*NN*DH;
    const float* invd = ws + DEN_OFF + (size_t)(b*NH + hh)*KN*DH;
    float*       agg  = ws + AGG_OFF + (size_t)(b*NH + hh)*NN*DH;

    int i0 = ic*8 + w*2;
    #pragma unroll
    for (int ii=0; ii<2; ii++){
        int i = i0 + ii;
        float4 av = *(const float4*)(Abuf + (size_t)i*HID + 4*dd);
        float acc = 0.f;
        for (int sg=0; sg<40; sg++){
            int j = sg*8 + g;
            bool jv = (j < KN);
            int jj = jv ? j : (KN-1);
            int p = idx[i*KN + jj];
            float4 bv = *(const float4*)(Bbuf + (size_t)p*HID + 4*dd);
            float r0 = fmaxf(av.x-bv.x, 0.f), r1 = fmaxf(av.y-bv.y, 0.f);
            float r2 = fmaxf(av.z-bv.z, 0.f), r3 = fmaxf(av.w-bv.w, 0.f);
            float pr[8];
            #pragma unroll
            for (int m=0; m<8; m++)
                pr[m] = fmaf(w2s[m][0],r0, fmaf(w2s[m][1],r1, fmaf(w2s[m][2],r2, w2s[m][3]*r3)));
            float sim = butterfly8(pr, dd) + b2v;
            float attn = jv ? (__expf(sim) * invd[(size_t)jj*DH + dd]) : 0.f;
            acc = fmaf(attn, Vbuf[(size_t)p*DH + dd], acc);
        }
        // reduce over the 8 slot-groups (lanes stride 8, same dd)
        acc += __shfl_xor(acc, 8, 64);
        acc += __shfl_xor(acc, 16, 64);
        acc += __shfl_xor(acc, 32, 64);
        if (g == 0) agg[(size_t)i*DH + dd] = acc;
    }
}

// ---------------- K5: out = agg @ w_out + b_out ----------------
__global__ void out_kernel(const float* __restrict__ w_out, const float* __restrict__ b_out,
                           const float* __restrict__ ws, float* __restrict__ out){
    int t = blockIdx.x*256 + threadIdx.x;
    if (t >= BB*NN*DIM) return;
    int c = t % DIM;
    int p = (t / DIM) % NN;
    int b = t / (DIM*NN);
    const float* agg = ws + AGG_OFF;
    float s = b_out[c];
    #pragma unroll
    for (int f=0; f<32; f++){
        int hh = f >> 3, d = f & 7;
        s = fmaf(agg[(((size_t)(b*NH + hh)*NN) + p)*DH + d], w_out[f*DIM + c], s);
    }
    out[t] = s;
}

extern "C" void kernel_launch(void* const* d_in, const int* in_sizes, int n_in,
                              void* d_out, int out_size, void* d_ws, size_t ws_size,
                              hipStream_t stream){
    const float* x     = (const float*)d_in[0];
    const int*   idx   = (const int*)d_in[1];
    const float* w_qkv = (const float*)d_in[2];
    const float* w1    = (const float*)d_in[3];
    const float* b1    = (const float*)d_in[4];
    const float* w2    = (const float*)d_in[5];
    const float* b2    = (const float*)d_in[6];
    const float* w_out = (const float*)d_in[7];
    const float* b_out = (const float*)d_in[8];
    float* ws  = (float*)d_ws;
    float* out = (float*)d_out;

    // zero the softmax denominators (ws is poisoned, not re-zeroed between replays)
    hipMemsetAsync(ws + DEN_OFF, 0, DEN_SZ*sizeof(float), stream);

    qkv_kernel  <<<(BB*NN*96 + 255)/256, 256, 0, stream>>>(x, w_qkv, ws);
    ab_kernel   <<<(BB*NH*NN*HID + 255)/256, 256, 0, stream>>>(w1, b1, ws);
    pass1_kernel<<<dim3(320, NH, BB), 256, 0, stream>>>(idx, w2, b2, ws);
    invden_kernel<<<(DEN_SZ + 255)/256, 256, 0, stream>>>(ws);
    pass2_kernel<<<dim3(288, NH, BB), 256, 0, stream>>>(idx, w2, b2, ws);
    out_kernel  <<<(BB*NN*DIM + 255)/256, 256, 0, stream>>>(w_out, b_out, ws, out);
}

// Round 4
// 207.066 us; speedup vs baseline: 3.0566x; 2.3875x over previous
//
#include <hip/hip_runtime.h>
#include <hip/hip_bf16.h>

// Problem constants (from reference setup_inputs)
#define BB 2
#define NH 4
#define NN 2304
#define DIM 64
#define DH 8
#define HID 32
#define KN 314   // neighbors per point

// Workspace layout (floats):
#define QKV_OFF 0
#define QKV_SZ  (BB*NN*96)            // 442368
#define A_OFF   (QKV_OFF + QKV_SZ)
#define A_SZ    (BB*NH*NN*HID)        // 589824
#define BK_OFF  (A_OFF + A_SZ)
#define BK_SZ   (BB*NH*NN*HID)
#define V_OFF   (BK_OFF + BK_SZ)
#define V_SZ    (BB*NH*NN*DH)         // 147456
#define DEN_OFF (V_OFF + V_SZ)
#define DEN_SZ  (BB*NH*KN*DH)         // 20096
#define AGG_OFF (DEN_OFF + DEN_SZ)
#define AGG_SZ  (BB*NH*NN*DH)         // 147456
#define NUM_OFF (AGG_OFF + AGG_SZ)    // 1937024
#define NUM_SZ  ((size_t)BB*NH*NN*KN*DH)  // 46301184 floats = 185.2 MB
#define WS_NEED_BYTES ((size_t)(NUM_OFF + NUM_SZ)*4)

typedef float v2f __attribute__((ext_vector_type(2)));
#define SWZ(x, imm) __int_as_float(__builtin_amdgcn_ds_swizzle(__float_as_int(x), imm))

// ---------------- K1: qkv = x @ w_qkv ----------------
__global__ void qkv_kernel(const float* __restrict__ x, const float* __restrict__ w_qkv, float* ws){
    int t = blockIdx.x*256 + threadIdx.x;
    if (t >= BB*NN*96) return;
    int c = t % 96;
    int p = (t / 96) % NN;
    int b = t / (96*NN);
    const float* xr = x + (b*NN + p)*DIM;
    float acc = 0.f;
    #pragma unroll 8
    for (int dd=0; dd<DIM; dd++)
        acc = fmaf(xr[dd], w_qkv[dd*96 + c], acc);
    ws[QKV_OFF + (b*NN + p)*96 + c] = acc;
}

// ---------------- K2: A = w1.q + b1 ; Bk = w1.k ; V copy ----------------
__global__ void ab_kernel(const float* __restrict__ w1, const float* __restrict__ b1, float* ws){
    int t = blockIdx.x*256 + threadIdx.x;
    if (t >= BB*NH*NN*HID) return;
    int e  = t % HID;
    int p  = (t / HID) % NN;
    int hh = (t / (HID*NN)) % NH;
    int b  = t / (HID*NN*NH);
    const float* qkv = ws + QKV_OFF + (b*NN + p)*96;
    const float* w1r = w1 + (hh*HID + e)*DH;
    float sa = b1[hh*HID + e];
    float sb = 0.f;
    #pragma unroll
    for (int d=0; d<DH; d++){
        float wv = w1r[d];
        sa = fmaf(wv, qkv[hh*DH + d],      sa);
        sb = fmaf(wv, qkv[32 + hh*DH + d], sb);
    }
    int base = ((b*NH + hh)*NN + p);
    ws[A_OFF  + base*HID + e] = sa;
    ws[BK_OFF + base*HID + e] = sb;
    if (e < DH)
        ws[V_OFF + base*DH + e] = qkv[64 + hh*DH + e];
}

// w2 slices in bit-reversed d order (so split-butterfly lands d=dd on lane dd)
__device__ __forceinline__ void load_w2p(const float* __restrict__ w2, int hh, int dd,
                                         v2f w2a[8], v2f w2b[8]){
    #pragma unroll
    for (int m=0; m<8; m++){
        int d = ((m&1)<<2) | (m&2) | ((m>>2)&1);   // bitrev3(m)
        const float* wp = w2 + (hh*DH + d)*HID + 4*dd;
        v2f a; a.x = wp[0]; a.y = wp[1];
        v2f b; b.x = wp[2]; b.y = wp[3];
        w2a[m] = a; w2b[m] = b;
    }
}

// partials pr[8] (bit-rev d order) -> full sim for d=dd on lane dd (8-lane group)
__device__ __forceinline__ float butterfly8s(float pr[8], int b0, int b1, int b2b){
    float q[4];
    #pragma unroll
    for (int t=0; t<4; t++){
        float send = b0 ? pr[t]   : pr[4+t];
        float keep = b0 ? pr[4+t] : pr[t];
        q[t] = keep + SWZ(send, 0x41F);      // xor 1
    }
    float r[2];
    #pragma unroll
    for (int t=0; t<2; t++){
        float send = b1 ? q[t]   : q[2+t];
        float keep = b1 ? q[2+t] : q[t];
        r[t] = keep + SWZ(send, 0x81F);      // xor 2
    }
    float send = b2b ? r[0] : r[1];
    float keep = b2b ? r[1] : r[0];
    return keep + SWZ(send, 0x101F);         // xor 4
}

// one i-iteration of pass1: returns exp(sim), optionally stores num
template<bool BIG>
__device__ __forceinline__ float p1_body(int i, const int* __restrict__ idxc,
        const float* __restrict__ Abuf, const float* __restrict__ Bbuf,
        const v2f* __restrict__ w2a, const v2f* __restrict__ w2b, float b2v,
        int b0, int b1, int b2b, bool jv, float* __restrict__ nump)
{
    int p = idxc[(size_t)i*KN];
    float4 avv = *(const float4*)(Abuf + (size_t)i*HID);
    float4 bvv = *(const float4*)(Bbuf + (size_t)p*HID);
    v2f a0; a0.x=avv.x; a0.y=avv.y;
    v2f a1; a1.x=avv.z; a1.y=avv.w;
    v2f c0; c0.x=bvv.x; c0.y=bvv.y;
    v2f c1; c1.x=bvv.z; c1.y=bvv.w;
    v2f z;  z.x=0.f; z.y=0.f;
    v2f r0 = __builtin_elementwise_max(a0-c0, z);
    v2f r1 = __builtin_elementwise_max(a1-c1, z);
    float pr[8];
    #pragma unroll
    for (int m=0; m<8; m++){
        v2f t = w2a[m]*r0;
        t = __builtin_elementwise_fma(w2b[m], r1, t);
        pr[m] = t.x + t.y;
    }
    float sim = butterfly8s(pr, b0, b1, b2b) + b2v;
    float nm = __expf(sim);
    if (BIG && jv) nump[(size_t)i*KN*DH] = nm;
    return nm;
}

// ---------------- K3: pass 1 — den[j,d] = sum_i exp(sim); optionally store num ----------------
// grid: (640, NH, BB); blockIdx.x = sg*16 + ic ; block = 256 (4 waves), 36 i's per wave
template<bool BIG>
__global__ __launch_bounds__(256, 6) void pass1_kernel(const int* __restrict__ idx,
                                                       const float* __restrict__ w2,
                                                       const float* __restrict__ b2, float* ws){
    int sgic = blockIdx.x, hh = blockIdx.y, b = blockIdx.z;
    int sg = sgic >> 4, ic = sgic & 15;
    int w = threadIdx.x >> 6, lane = threadIdx.x & 63;
    int g = lane >> 3, dd = lane & 7;
    int b0 = dd&1, b1 = (dd>>1)&1, b2b = (dd>>2)&1;
    int j = sg*8 + g;
    bool jv = (j < KN);
    int jj = jv ? j : (KN-1);
    int bh = b*NH + hh;

    v2f w2a[8], w2b[8];
    load_w2p(w2, hh, dd, w2a, w2b);
    float b2v = b2[hh*DH + dd];

    const float* Abuf = ws + A_OFF  + (size_t)bh*NN*HID + 4*dd;
    const float* Bbuf = ws + BK_OFF + (size_t)bh*NN*HID + 4*dd;
    float* nump = ws + NUM_OFF + (size_t)bh*NN*KN*DH + (size_t)jj*DH + dd;
    const int* idxc = idx + jj;

    float d0 = 0.f, d1 = 0.f;
    int i0 = ic*144 + w*36;
    for (int ii=0; ii<36; ii+=2){
        d0 += p1_body<BIG>(i0+ii,   idxc, Abuf, Bbuf, w2a, w2b, b2v, b0,b1,b2b, jv, nump);
        d1 += p1_body<BIG>(i0+ii+1, idxc, Abuf, Bbuf, w2a, w2b, b2v, b0,b1,b2b, jv, nump);
    }
    float den_acc = d0 + d1;
    if (!jv) den_acc = 0.f;

    __shared__ float red[256];
    red[threadIdx.x] = den_acc;
    __syncthreads();
    if (w == 0 && jv){
        float s = red[lane] + red[lane+64] + red[lane+128] + red[lane+192];
        atomicAdd(ws + DEN_OFF + ((size_t)bh*KN + j)*DH + dd, s);
    }
}

// ---------------- K3.5: invert den in place ----------------
__global__ void invden_kernel(float* ws){
    int t = blockIdx.x*256 + threadIdx.x;
    if (t < DEN_SZ){
        float* d = ws + DEN_OFF;
        d[t] = 1.0f / d[t];
    }
}

// ---------------- K4-fast: agg[i,d] = sum_j num[i,j,d]*invd[j,d]*v[p,d] ----------------
// grid: (576, NH, BB); block 256 = 4 waves, 1 i per wave
__global__ __launch_bounds__(256) void pass2f_kernel(const int* __restrict__ idx, float* ws){
    int hh = blockIdx.y, b = blockIdx.z;
    int w = threadIdx.x >> 6, lane = threadIdx.x & 63;
    int g = lane >> 3, dd = lane & 7;
    int bh = b*NH + hh;

    __shared__ float invs[KN*DH];
    {
        const float* invd = ws + DEN_OFF + (size_t)bh*KN*DH;
        for (int t = threadIdx.x; t < KN*DH; t += 256) invs[t] = invd[t];
    }
    __syncthreads();

    int i = blockIdx.x*4 + w;
    const float* Vbuf = ws + V_OFF  + (size_t)bh*NN*DH;
    const float* nump = ws + NUM_OFF + ((size_t)bh*NN + i)*KN*DH;
    const int*   idxr = idx + (size_t)i*KN;
    float* agg = ws + AGG_OFF + (size_t)bh*NN*DH;

    float acc = 0.f;
    #pragma unroll 2
    for (int sg=0; sg<40; sg++){
        int j = sg*8 + g;
        bool jvv = (j < KN);
        int jj = jvv ? j : (KN-1);
        int p = idxr[jj];
        float nm = nump[(size_t)jj*DH + dd];
        float att = jvv ? nm * invs[jj*DH + dd] : 0.f;
        acc = fmaf(att, Vbuf[(size_t)p*DH + dd], acc);
    }
    acc += __shfl_xor(acc, 8, 64);
    acc += __shfl_xor(acc, 16, 64);
    acc += __shfl_xor(acc, 32, 64);
    if (g == 0) agg[(size_t)i*DH + dd] = acc;
}

// ---------------- K4-fallback: recompute sim (round-3 verbatim) ----------------
__device__ __forceinline__ void load_w2s(const float* __restrict__ w2, int hh, int dd, float w2s[8][4]){
    #pragma unroll
    for (int m=0; m<8; m++){
        int d = ((m&1)<<2) | (m&2) | ((m>>2)&1);
        const float* wp = w2 + (hh*DH + d)*HID + 4*dd;
        w2s[m][0]=wp[0]; w2s[m][1]=wp[1]; w2s[m][2]=wp[2]; w2s[m][3]=wp[3];
    }
}
__device__ __forceinline__ float butterfly8(float pr[8], int dd){
    int b0 = dd&1, b1 = (dd>>1)&1, b2b = (dd>>2)&1;
    float q[4];
    #pragma unroll
    for (int t=0; t<4; t++){
        float send = pr[4*(1-b0)+t];
        float recv = __shfl_xor(send, 1, 64);
        q[t] = pr[4*b0+t] + recv;
    }
    float r[2];
    #pragma unroll
    for (int t=0; t<2; t++){
        float send = q[2*(1-b1)+t];
        float recv = __shfl_xor(send, 2, 64);
        r[t] = q[2*b1+t] + recv;
    }
    float send = r[1-b2b];
    float recv = __shfl_xor(send, 4, 64);
    return r[b2b] + recv;
}
__global__ __launch_bounds__(256) void pass2_kernel(const int* __restrict__ idx,
                                                    const float* __restrict__ w2,
                                                    const float* __restrict__ b2, float* ws){
    int ic = blockIdx.x, hh = blockIdx.y, b = blockIdx.z;
    int w = threadIdx.x >> 6, lane = threadIdx.x & 63;
    int g = lane >> 3, dd = lane & 7;

    float w2s[8][4];
    load_w2s(w2, hh, dd, w2s);
    float b2v = b2[hh*DH + dd];

    const float* Abuf = ws + A_OFF  + (size_t)(b*NH + hh)*NN*HID;
    const float* Bbuf = ws + BK_OFF + (size_t)(b*NH + hh)*NN*HID;
    const float* Vbuf = ws + V_OFF  + (size_t)(b*NH + hh)*NN*DH;
    const float* invd = ws + DEN_OFF + (size_t)(b*NH + hh)*KN*DH;
    float*       agg  = ws + AGG_OFF + (size_t)(b*NH + hh)*NN*DH;

    int i0 = ic*8 + w*2;
    #pragma unroll
    for (int ii=0; ii<2; ii++){
        int i = i0 + ii;
        float4 av = *(const float4*)(Abuf + (size_t)i*HID + 4*dd);
        float acc = 0.f;
        for (int sg=0; sg<40; sg++){
            int j = sg*8 + g;
            bool jvv = (j < KN);
            int jj = jvv ? j : (KN-1);
            int p = idx[i*KN + jj];
            float4 bv = *(const float4*)(Bbuf + (size_t)p*HID + 4*dd);
            float r0 = fmaxf(av.x-bv.x, 0.f), r1 = fmaxf(av.y-bv.y, 0.f);
            float r2 = fmaxf(av.z-bv.z, 0.f), r3 = fmaxf(av.w-bv.w, 0.f);
            float pr[8];
            #pragma unroll
            for (int m=0; m<8; m++)
                pr[m] = fmaf(w2s[m][0],r0, fmaf(w2s[m][1],r1, fmaf(w2s[m][2],r2, w2s[m][3]*r3)));
            float sim = butterfly8(pr, dd) + b2v;
            float attn = jvv ? (__expf(sim) * invd[(size_t)jj*DH + dd]) : 0.f;
            acc = fmaf(attn, Vbuf[(size_t)p*DH + dd], acc);
        }
        acc += __shfl_xor(acc, 8, 64);
        acc += __shfl_xor(acc, 16, 64);
        acc += __shfl_xor(acc, 32, 64);
        if (g == 0) agg[(size_t)i*DH + dd] = acc;
    }
}

// ---------------- K5: out = agg @ w_out + b_out ----------------
__global__ void out_kernel(const float* __restrict__ w_out, const float* __restrict__ b_out,
                           const float* __restrict__ ws, float* __restrict__ out){
    int t = blockIdx.x*256 + threadIdx.x;
    if (t >= BB*NN*DIM) return;
    int c = t % DIM;
    int p = (t / DIM) % NN;
    int b = t / (DIM*NN);
    const float* agg = ws + AGG_OFF;
    float s = b_out[c];
    #pragma unroll
    for (int f=0; f<32; f++){
        int hh = f >> 3, d = f & 7;
        s = fmaf(agg[(((size_t)(b*NH + hh)*NN) + p)*DH + d], w_out[f*DIM + c], s);
    }
    out[t] = s;
}

extern "C" void kernel_launch(void* const* d_in, const int* in_sizes, int n_in,
                              void* d_out, int out_size, void* d_ws, size_t ws_size,
                              hipStream_t stream){
    const float* x     = (const float*)d_in[0];
    const int*   idx   = (const int*)d_in[1];
    const float* w_qkv = (const float*)d_in[2];
    const float* w1    = (const float*)d_in[3];
    const float* b1    = (const float*)d_in[4];
    const float* w2    = (const float*)d_in[5];
    const float* b2    = (const float*)d_in[6];
    const float* w_out = (const float*)d_in[7];
    const float* b_out = (const float*)d_in[8];
    float* ws  = (float*)d_ws;
    float* out = (float*)d_out;

    bool big = (ws_size >= WS_NEED_BYTES);

    hipMemsetAsync(ws + DEN_OFF, 0, DEN_SZ*sizeof(float), stream);

    qkv_kernel<<<(BB*NN*96 + 255)/256, 256, 0, stream>>>(x, w_qkv, ws);
    ab_kernel <<<(BB*NH*NN*HID + 255)/256, 256, 0, stream>>>(w1, b1, ws);
    if (big){
        pass1_kernel<true ><<<dim3(640, NH, BB), 256, 0, stream>>>(idx, w2, b2, ws);
        invden_kernel<<<(DEN_SZ + 255)/256, 256, 0, stream>>>(ws);
        pass2f_kernel<<<dim3(576, NH, BB), 256, 0, stream>>>(idx, ws);
    } else {
        pass1_kernel<false><<<dim3(640, NH, BB), 256, 0, stream>>>(idx, w2, b2, ws);
        invden_kernel<<<(DEN_SZ + 255)/256, 256, 0, stream>>>(ws);
        pass2_kernel<<<dim3(288, NH, BB), 256, 0, stream>>>(idx, w2, b2, ws);
    }
    out_kernel<<<(BB*NN*DIM + 255)/256, 256, 0, stream>>>(w_out, b_out, ws, out);
}